// Round 5
// baseline (31.781 us; speedup 1.0000x reference)
//
#include <hip/hip_runtime.h>

// ESN scan: out[b,c,t,r] = s_t, s_t = tanh(x[b,c,t]*w[r] + s_{t-1}*d[r]).
// B=32 C=8 T=512 R=256. 256 blocks (one per (b,c)) x 128 threads; thread i
// owns TWO chains: r=i and r=i+128 (independent recurrences -> 2-way ILP on
// the serial chain, which at 1 wave/SIMD is otherwise fully latency-exposed:
// observed 125 cy/step ~= chain {exp2, add, rcp, fma} with quarter-rate
// transcendental dependent latency).
//
// R1: x staged in LDS -> no global loads in loop (stores never vmcnt-waited).
// R2: chain shortened; stored value off-chain.            [neutral]
// R3: dwordx4 stores via LDS transpose.                   [slightly worse, reverted]
// R4: 2 chains/thread ILP (this round).

constexpr int Bdim = 32;
constexpr int Cdim = 8;
constexpr int Tdim = 512;
constexpr int Rdim = 256;
constexpr int T4   = Tdim / 4;    // 128 float4 of x per row
constexpr int NT   = 128;         // threads per block

__device__ __forceinline__ float fast_exp2(float v) {
#if defined(__has_builtin)
#if __has_builtin(__builtin_amdgcn_exp2f)
    return __builtin_amdgcn_exp2f(v);
#else
    return exp2f(v);
#endif
#else
    return exp2f(v);
#endif
}

__global__ __launch_bounds__(NT, 1) void esn_scan_kernel(
    const float* __restrict__ x,     // [B*C, T]
    const float* __restrict__ W_in,  // [R] (R,1 flattened)
    const float* __restrict__ d,     // [R]
    float* __restrict__ out)         // [B*C, T, R]
{
    const int bc = blockIdx.x;
    const int i  = threadIdx.x;      // 0..127; chains r=i and r=i+128

    // tanh(a) = 1 - 2/(exp2(K*a)+1), K = 2*log2(e); fold K into w,d.
    const float K     = 2.0f * 1.4426950408889634f;
    const float wkA   = W_in[i] * K;
    const float dkA   = d[i] * K;
    const float m2dkA = -2.0f * dkA;
    const float wkB   = W_in[i + 128] * K;
    const float dkB   = d[i + 128] * K;
    const float m2dkB = -2.0f * dkB;

    __shared__ float4 xs4[T4];       // 2 KiB
    {
        const float4* __restrict__ x4 = reinterpret_cast<const float4*>(x + bc * Tdim);
        xs4[i] = x4[i];              // 128 threads x 16B = whole row
    }
    __syncthreads();

    float* __restrict__ o = out + (size_t)bc * Tdim * Rdim + i;  // chain A base
    // chain B = o + 128 (fits imm offset alongside A's)

    // Group = 8 steps = 2 float4 of x (shared by both chains).
    float4 a0 = xs4[0], a1 = xs4[1];
    float4 b0 = xs4[2], b1 = xs4[3];

    float eargA = a0.x * wkA;        // t=0 arg (s_init = 0)
    float eargB = a0.x * wkB;

    #pragma unroll 1
    for (int g = 0; g < Tdim / 8; ++g) {
        int pf = 2 * g + 4; if (pf > T4 - 2) pf = T4 - 2;
        float4 c0 = xs4[pf], c1 = xs4[pf + 1];

        // Off-chain successor-arg pre-adds for both chains.
        float preA[8], preB[8];
        preA[0] = fmaf(a0.y, wkA, dkA);  preB[0] = fmaf(a0.y, wkB, dkB);
        preA[1] = fmaf(a0.z, wkA, dkA);  preB[1] = fmaf(a0.z, wkB, dkB);
        preA[2] = fmaf(a0.w, wkA, dkA);  preB[2] = fmaf(a0.w, wkB, dkB);
        preA[3] = fmaf(a1.x, wkA, dkA);  preB[3] = fmaf(a1.x, wkB, dkB);
        preA[4] = fmaf(a1.y, wkA, dkA);  preB[4] = fmaf(a1.y, wkB, dkB);
        preA[5] = fmaf(a1.z, wkA, dkA);  preB[5] = fmaf(a1.z, wkB, dkB);
        preA[6] = fmaf(a1.w, wkA, dkA);  preB[6] = fmaf(a1.w, wkB, dkB);
        preA[7] = fmaf(b0.x, wkA, dkA);  preB[7] = fmaf(b0.x, wkB, dkB);

        float* ob  = o + (size_t)(g * 8) * Rdim;   // steps 0..3
        float* ob4 = ob + (size_t)4 * Rdim;        // steps 4..7 (imm < 4096B)

        #pragma unroll
        for (int j = 0; j < 4; ++j) {
            float eA  = fast_exp2(eargA);
            float eB  = fast_exp2(eargB);
            float rcA = __builtin_amdgcn_rcpf(eA + 1.0f);
            float rcB = __builtin_amdgcn_rcpf(eB + 1.0f);
            ob[j * Rdim]       = fmaf(-2.0f, rcA, 1.0f);
            ob[j * Rdim + 128] = fmaf(-2.0f, rcB, 1.0f);
            eargA = fmaf(m2dkA, rcA, preA[j]);
            eargB = fmaf(m2dkB, rcB, preB[j]);
        }
        #pragma unroll
        for (int j = 0; j < 4; ++j) {
            float eA  = fast_exp2(eargA);
            float eB  = fast_exp2(eargB);
            float rcA = __builtin_amdgcn_rcpf(eA + 1.0f);
            float rcB = __builtin_amdgcn_rcpf(eB + 1.0f);
            ob4[j * Rdim]       = fmaf(-2.0f, rcA, 1.0f);
            ob4[j * Rdim + 128] = fmaf(-2.0f, rcB, 1.0f);
            eargA = fmaf(m2dkA, rcA, preA[j + 4]);
            eargB = fmaf(m2dkB, rcB, preB[j + 4]);
        }

        a0 = b0; a1 = b1;
        b0 = c0; b1 = c1;
    }
}

extern "C" void kernel_launch(void* const* d_in, const int* in_sizes, int n_in,
                              void* d_out, int out_size, void* d_ws, size_t ws_size,
                              hipStream_t stream) {
    const float* x    = (const float*)d_in[0];  // [B,C,T]
    const float* W_in = (const float*)d_in[1];  // [R,1]
    const float* d    = (const float*)d_in[2];  // [R]
    float* out        = (float*)d_out;          // [B,C,T,R]

    dim3 grid(Bdim * Cdim);
    dim3 block(NT);
    esn_scan_kernel<<<grid, block, 0, stream>>>(x, W_in, d, out);
}

// Round 6
// 27.118 us; speedup vs baseline: 1.1720x; 1.1720x over previous
//
#include <hip/hip_runtime.h>

// ESN scan: out[b,c,t,r] = s_t, s_t = tanh(x[b,c,t]*w[r] + s_{t-1}*d[r]).
// B=32 C=8 T=512 R=256. 256 blocks x 256 threads, one thread per r-chain.
//
// R1: x staged in LDS -> no global loads in loop.            [34.6 -> 26.7]
// R2: chain = {exp2, add, rcp, fma}; stored value off-chain. [neutral]
// R3: dwordx4 stores via block-wide LDS transpose+barriers.  [-0.9us, reverted]
// R4: 2 chains/thread, 2 waves/CU.                           [-5us, reverted]
// R5: R3's wide stores WITHOUT barriers: wave-private LDS transpose.
//     Each wave: 16 ds_write_b32 (own 4KB region, wave-ordered, lgkmcnt only)
//     -> 4 ds_read_b128 -> 4 global_store_dwordx4 back-to-back (4KB burst).
//     Theory: store pipe is outstanding-bytes limited (R1/R2 8.2 B/cy/CU vs
//     fill kernel 11 B/cy/CU); bursted 1KB stores build queue depth.

constexpr int Bdim = 32;
constexpr int Cdim = 8;
constexpr int Tdim = 512;
constexpr int Rdim = 256;
constexpr int T4   = Tdim / 4;    // 128 float4 of x per row
constexpr int GS   = 16;          // steps per group
constexpr int NG   = Tdim / GS;   // 32 groups

__device__ __forceinline__ float fast_exp2(float v) {
#if defined(__has_builtin)
#if __has_builtin(__builtin_amdgcn_exp2f)
    return __builtin_amdgcn_exp2f(v);
#else
    return exp2f(v);
#endif
#else
    return exp2f(v);
#endif
}

__global__ __launch_bounds__(256, 1) void esn_scan_kernel(
    const float* __restrict__ x,     // [B*C, T]
    const float* __restrict__ W_in,  // [R] (R,1 flattened)
    const float* __restrict__ d,     // [R]
    float* __restrict__ out)         // [B*C, T, R]
{
    const int bc = blockIdx.x;
    const int r  = threadIdx.x;
    const int w  = r >> 6;     // wave 0..3
    const int l  = r & 63;     // lane 0..63

    // tanh(a) = 1 - 2/(exp2(K*a)+1), K = 2*log2(e); fold K into w,d.
    const float K    = 2.0f * 1.4426950408889634f;
    const float wk   = W_in[r] * K;
    const float dk   = d[r] * K;
    const float m2dk = -2.0f * dk;

    __shared__ float4 xs4[T4];          // 2 KiB: this row's x
    __shared__ float  sb[4][GS][64];    // 16 KiB: wave-private transpose scratch

    {
        const float4* __restrict__ x4 = reinterpret_cast<const float4*>(x + bc * Tdim);
        if (r < T4) xs4[r] = x4[r];
    }
    __syncthreads();   // only barrier in the kernel (x staging)

    float4* __restrict__ orow =
        reinterpret_cast<float4*>(out + (size_t)bc * Tdim * Rdim);

    // Group g consumes xs4[4g..4g+3]; current group in regs, prefetch next.
    float4 a0 = xs4[0], a1 = xs4[1], a2 = xs4[2], a3 = xs4[3];
    float earg = a0.x * wk;    // t=0 arg (s_init = 0)

    // Per-thread store geometry (constant over groups):
    //   this wave's r-range = w*64..w*64+63  -> float4 cols w*16..w*16+15
    //   lane l stores t-subrows (l>>4)+{0,4,8,12}, float4 col (l&15).
    const int tsub = l >> 4;
    const int col  = l & 15;

    #pragma unroll 1
    for (int g = 0; g < NG; ++g) {
        int pf = 4 * g + 4; if (pf > T4 - 4) pf = T4 - 4;   // clamp; tail dead
        float4 n0 = xs4[pf], n1 = xs4[pf + 1], n2 = xs4[pf + 2], n3 = xs4[pf + 3];

        // Off-chain successor-arg pre-adds: pre[j] = x_{t+1}*wk + dk.
        float pre[GS];
        pre[0]  = fmaf(a0.y, wk, dk);
        pre[1]  = fmaf(a0.z, wk, dk);
        pre[2]  = fmaf(a0.w, wk, dk);
        pre[3]  = fmaf(a1.x, wk, dk);
        pre[4]  = fmaf(a1.y, wk, dk);
        pre[5]  = fmaf(a1.z, wk, dk);
        pre[6]  = fmaf(a1.w, wk, dk);
        pre[7]  = fmaf(a2.x, wk, dk);
        pre[8]  = fmaf(a2.y, wk, dk);
        pre[9]  = fmaf(a2.z, wk, dk);
        pre[10] = fmaf(a2.w, wk, dk);
        pre[11] = fmaf(a3.x, wk, dk);
        pre[12] = fmaf(a3.y, wk, dk);
        pre[13] = fmaf(a3.z, wk, dk);
        pre[14] = fmaf(a3.w, wk, dk);
        pre[15] = fmaf(n0.x, wk, dk);   // next group's t0 (dead on last group)

        // 16 recurrence steps; s -> wave-private LDS (stride-1, conflict-free;
        // j is compile-time after unroll -> immediate ds offsets).
        #pragma unroll
        for (int j = 0; j < GS; ++j) {
            float e  = fast_exp2(earg);
            float rc = __builtin_amdgcn_rcpf(e + 1.0f);
            sb[w][j][l] = fmaf(-2.0f, rc, 1.0f);
            earg = fmaf(m2dk, rc, pre[j]);
        }

        // Wave-ordered LDS: reads below see this wave's writes (lgkmcnt only,
        // compiler inserts the wait). No __syncthreads.
        const float4* __restrict__ src =
            reinterpret_cast<const float4*>(&sb[w][0][0]);   // [16 t][16 f4cols]
        float4 v0 = src[(tsub     ) * 16 + col];
        float4 v1 = src[(tsub +  4) * 16 + col];
        float4 v2 = src[(tsub +  8) * 16 + col];
        float4 v3 = src[(tsub + 12) * 16 + col];

        // 4 x global_store_dwordx4, back-to-back 4KB burst per wave.
        const size_t base = (size_t)(g * GS + tsub) * 64 + (size_t)w * 16 + col;
        orow[base + 0 * 4 * 64] = v0;
        orow[base + 1 * 4 * 64] = v1;
        orow[base + 2 * 4 * 64] = v2;
        orow[base + 3 * 4 * 64] = v3;

        a0 = n0; a1 = n1; a2 = n2; a3 = n3;
    }
}

extern "C" void kernel_launch(void* const* d_in, const int* in_sizes, int n_in,
                              void* d_out, int out_size, void* d_ws, size_t ws_size,
                              hipStream_t stream) {
    const float* x    = (const float*)d_in[0];  // [B,C,T]
    const float* W_in = (const float*)d_in[1];  // [R,1]
    const float* d    = (const float*)d_in[2];  // [R]
    float* out        = (float*)d_out;          // [B,C,T,R]

    dim3 grid(Bdim * Cdim);
    dim3 block(Rdim);
    esn_scan_kernel<<<grid, block, 0, stream>>>(x, W_in, d, out);
}